// Round 1
// baseline (1349.165 us; speedup 1.0000x reference)
//
#include <hip/hip_runtime.h>

typedef __bf16 bf16;
typedef __bf16 bf16x8 __attribute__((ext_vector_type(8)));
typedef float f32x4 __attribute__((ext_vector_type(4)));

#define NJ 24
#define CIN_ 32
#define COUT_ 32
#define KT 15
#define PAD_ 7
#define NB 32
#define T_ 4096
#define NG 12           // pooled groups (24 joints -> 12)
#define KC 128          // 4 neighbor joints * 32 cin per pooled group
#define TT 128          // t-tile per block
#define ROWS (TT + KT - 1)   // 142 input rows incl. halo
#define PITCH 136       // bf16 per LDS row: 128 + 8 pad = 272 B (16B-aligned rows)

// ---------------------------------------------------------------------------
// Weight prep: pooled, masked, bf16 weights
// Wp[((g*15 + tap)*32 + cout)*128 + nj*32 + cin]
//   = 0.5 * sum_{j in {2g,2g+1}} mask[j,i] * W[j*32+cout][i*32+cin][tap],
//   i = 2g-1+nj  (zero outside skeleton)
// ---------------------------------------------------------------------------
__global__ __launch_bounds__(256) void wprep(const float* __restrict__ W,
                                             bf16* __restrict__ Wp) {
    int idx = blockIdx.x * 256 + threadIdx.x;     // [0, 12*15*32*128)
    int cin_f = idx & 127;
    int cout  = (idx >> 7) & 31;
    int gt    = idx >> 12;        // g*15 + tap
    int tap   = gt % 15;
    int g     = gt / 15;
    int nj    = cin_f >> 5;
    int cin   = cin_f & 31;
    int i     = 2 * g - 1 + nj;
    int j0 = 2 * g, j1 = 2 * g + 1;
    const int so = NJ * CIN_ * KT;   // 11520, stride of out-channel in W
    float v = 0.f;
    if (nj == 0) {
        if (i >= 0) v = W[(j0 * 32 + cout) * so + (i * 32 + cin) * 15 + tap];
    } else if (nj == 3) {
        if (i < NJ) v = W[(j1 * 32 + cout) * so + (i * 32 + cin) * 15 + tap];
    } else {
        v = W[(j0 * 32 + cout) * so + (i * 32 + cin) * 15 + tap]
          + W[(j1 * 32 + cout) * so + (i * 32 + cin) * 15 + tap];
    }
    Wp[idx] = (bf16)(0.5f * v);
}

// ---------------------------------------------------------------------------
// Main fused kernel: conv(Wp) + bias-pool + LeakyReLU
// block = (t-tile, group, batch); 256 threads = 4 waves
// wave computes 32 couts x 32 t via 2x2 tiles of mfma_f32_16x16x32_bf16
// ---------------------------------------------------------------------------
__global__ __launch_bounds__(256) void skconv(const float* __restrict__ x,
                                              const bf16* __restrict__ Wp,
                                              const float* __restrict__ bias,
                                              float* __restrict__ out) {
    __shared__ __align__(16) bf16 xs[ROWS * PITCH];

    const int tid = threadIdx.x;
    const int t0  = blockIdx.x * TT;
    const int g   = blockIdx.y;
    const int b   = blockIdx.z;

    // ---- stage x tile (128 ch x 142 t) to LDS, transposed to [t][cin], bf16
    const int cbase = (2 * g - 1) * 32;               // first neighbor joint ch
    const float* xb = x + (size_t)b * (NJ * CIN_) * T_;
    #pragma unroll
    for (int it = 0; it < (KC * ROWS) / 256; ++it) {  // 71 iterations exact
        int idx = tid + it * 256;
        int c   = idx / ROWS;
        int tl  = idx - c * ROWS;
        int gtt = t0 - PAD_ + tl;
        int gc  = cbase + c;
        float v = 0.f;
        if (gtt >= 0 && gtt < T_ && gc >= 0 && gc < NJ * CIN_)
            v = xb[gc * T_ + gtt];
        xs[tl * PITCH + c] = (bf16)v;
    }
    __syncthreads();

    const int lane = tid & 63;
    const int wave = tid >> 6;
    const int r    = lane & 15;     // A: cout row / B: t col / D: t col
    const int q    = lane >> 4;     // k-chunk quad
    const int woff = wave * 32;     // this wave's t offset within tile
    const int qo   = q * 8;

    f32x4 acc[2][2] = {};           // [mtile][ntile]

    const bf16* wg = Wp + (size_t)g * (KT * 32 * 128);
    for (int k = 0; k < KT; ++k) {
        const bf16* wr0   = wg + k * (32 * 128) + r * 128 + qo;
        const bf16* wr1   = wr0 + 16 * 128;
        const bf16* xrow0 = xs + (woff + r + k) * PITCH + qo;
        const bf16* xrow1 = xrow0 + 16 * PITCH;
        #pragma unroll
        for (int cc = 0; cc < 4; ++cc) {
            bf16x8 a0 = *(const bf16x8*)(wr0 + cc * 32);
            bf16x8 a1 = *(const bf16x8*)(wr1 + cc * 32);
            bf16x8 b0 = *(const bf16x8*)(xrow0 + cc * 32);
            bf16x8 b1 = *(const bf16x8*)(xrow1 + cc * 32);
            acc[0][0] = __builtin_amdgcn_mfma_f32_16x16x32_bf16(a0, b0, acc[0][0], 0, 0, 0);
            acc[0][1] = __builtin_amdgcn_mfma_f32_16x16x32_bf16(a0, b1, acc[0][1], 0, 0, 0);
            acc[1][0] = __builtin_amdgcn_mfma_f32_16x16x32_bf16(a1, b0, acc[1][0], 0, 0, 0);
            acc[1][1] = __builtin_amdgcn_mfma_f32_16x16x32_bf16(a1, b1, acc[1][1], 0, 0, 0);
        }
    }

    // ---- epilogue: pooled bias + LeakyReLU(0.2), store fp32
    float* ob = out + (size_t)b * (NG * COUT_) * T_;
    #pragma unroll
    for (int mt = 0; mt < 2; ++mt) {
        #pragma unroll
        for (int reg = 0; reg < 4; ++reg) {
            int cout = mt * 16 + q * 4 + reg;       // D row = quad*4 + reg
            float bp = 0.5f * (bias[(2 * g) * 32 + cout] +
                               bias[(2 * g + 1) * 32 + cout]);
            #pragma unroll
            for (int nt = 0; nt < 2; ++nt) {
                float v = acc[mt][nt][reg] + bp;
                v = (v >= 0.f) ? v : 0.2f * v;
                ob[(size_t)(g * COUT_ + cout) * T_ + (t0 + woff + nt * 16 + r)] = v;
            }
        }
    }
}

// ---------------------------------------------------------------------------
extern "C" void kernel_launch(void* const* d_in, const int* in_sizes, int n_in,
                              void* d_out, int out_size, void* d_ws, size_t ws_size,
                              hipStream_t stream) {
    (void)in_sizes; (void)n_in; (void)out_size; (void)ws_size;
    const float* x    = (const float*)d_in[0];
    const float* W    = (const float*)d_in[1];
    const float* bias = (const float*)d_in[2];
    // d_in[3] (mask) and d_in[4] (pool_pairs) are fixed topology; encoded here.
    bf16* Wp   = (bf16*)d_ws;        // 12*15*32*128 bf16 = 1.47 MB
    float* out = (float*)d_out;

    wprep<<<dim3((NG * KT * 32 * 128) / 256), dim3(256), 0, stream>>>(W, Wp);
    skconv<<<dim3(T_ / TT, NG, NB), dim3(256), 0, stream>>>(x, Wp, bias, out);
}